// Round 7
// baseline (504.870 us; speedup 1.0000x reference)
//
#include <hip/hip_runtime.h>
#include <hip/hip_bf16.h>
#include <math.h>

typedef __bf16 bf16_t;
typedef float f32x4 __attribute__((ext_vector_type(4)));
typedef bf16_t bf16x8 __attribute__((ext_vector_type(8)));

#define BM 128
#define BN 128
#define BKT 32
#define NT 16    // 512 / BKT

// async global->LDS, 16B per lane; LDS dest = wave-uniform base + lane*16 (linear)
#define GLD_LDS16(gp, lp) __builtin_amdgcn_global_load_lds( \
    (const __attribute__((address_space(1))) void*)(gp), \
    (__attribute__((address_space(3))) void*)(lp), 16, 0, 0)

// ---------------- weight prep: jobs 0..5 transpose+cast, job 6 plain cast (dw2) ----------------
struct TC7 { const float* src[7]; bf16_t* dst[7]; };
__global__ __launch_bounds__(256) void tcast7_kernel(TC7 tc) {
  int job = blockIdx.x >> 10;
  int idx = (blockIdx.x & 1023) * 256 + threadIdx.x;
  if (job < 6) {
    int n = idx >> 9, k = idx & 511;
    tc.dst[job][idx] = (bf16_t)tc.src[job][k * 512 + n];
  } else {
    tc.dst[job][idx] = (bf16_t)tc.src[job][idx];
  }
}

// ---------------- cc[n] = sum_d db2[d]*gw1[d][n] + gb1[n] ----------------
__global__ __launch_bounds__(256) void cc_kernel(const float* __restrict__ db2, const float* __restrict__ gw1,
                                                 const float* __restrict__ gb1, float* __restrict__ cc) {
  int n = blockIdx.x * 256 + threadIdx.x;
  float s = gb1[n];
  for (int d = 0; d < 512; ++d) s = fmaf(db2[d], gw1[d * 512 + n], s);
  cc[n] = s;
}

// ---------------- KNN: one WAVE per query; per-lane u64 keys in registers ----------------
__global__ __launch_bounds__(256) void knn_kernel(const float* __restrict__ xyz, int* __restrict__ knn) {
  __shared__ float sx[2048], sy[2048], sz[2048], sq[2048];
  int tid = threadIdx.x;
  int lane = tid & 63, wave = tid >> 6;
  int gq = blockIdx.x * 4 + wave;
  int b  = gq >> 11;
  int base = b << 11;
  for (int p = tid; p < 2048; p += 256) {
    float x = xyz[(base + p) * 3 + 0];
    float y = xyz[(base + p) * 3 + 1];
    float z = xyz[(base + p) * 3 + 2];
    sx[p] = x; sy[p] = y; sz[p] = z;
    sq[p] = __fadd_rn(__fadd_rn(__fmul_rn(x, x), __fmul_rn(y, y)), __fmul_rn(z, z));
  }
  __syncthreads();
  int iq = gq & 2047;
  float qx = sx[iq], qy = sy[iq], qz = sz[iq], sqi = sq[iq];

  unsigned long long key[32];
  #pragma unroll
  for (int j = 0; j < 32; ++j) {
    int p = lane + j * 64;
    float d = __fmul_rn(sx[p], qx);
    d = fmaf(sy[p], qy, d);
    d = fmaf(sz[p], qz, d);
    float dist = __fsub_rn(__fadd_rn(sqi, sq[p]), __fmul_rn(2.0f, d));
    unsigned int bits = __float_as_uint(dist);
    unsigned int sk = bits ^ (unsigned int)(((int)bits >> 31) | 0x80000000);
    key[j] = ((unsigned long long)sk << 32) | (unsigned int)p;
  }

  int r = 0;
  #pragma unroll 1
  for (int s = 0; s < 16; ++s) {
    unsigned long long m = key[0];
    #pragma unroll
    for (int j = 1; j < 32; ++j) m = (key[j] < m) ? key[j] : m;
    #pragma unroll
    for (int off = 32; off > 0; off >>= 1) {
      unsigned long long o = (unsigned long long)__shfl_xor((long long)m, off);
      if (o < m) m = o;
    }
    if (lane == s) r = base + (int)(m & 0xFFFFFFFFu);
    #pragma unroll
    for (int j = 0; j < 32; ++j) key[j] = (key[j] == m) ? ~0ULL : key[j];
  }
  if (lane < 16) knn[gq * 16 + lane] = r;
}

// ---------------- x = points @ fc1_w + fc1_b -> bf16 [4096][512] ----------------
__global__ __launch_bounds__(256) void xfeat_kernel(const float* __restrict__ points, const float* __restrict__ fc1_w,
                                                    const float* __restrict__ fc1_b, bf16_t* __restrict__ xb) {
  __shared__ float p[32];
  int m = blockIdx.x, tid = threadIdx.x;
  if (tid < 32) p[tid] = points[m * 32 + tid];
  __syncthreads();
  for (int c = tid; c < 512; c += 256) {
    float a = fc1_b[c];
    #pragma unroll
    for (int kk = 0; kk < 32; ++kk) a = fmaf(p[kk], fc1_w[kk * 512 + c], a);
    xb[m * 512 + c] = (bf16_t)a;
  }
}

// ---------------- res = res_mid @ fc2_w + fc2_b + points -> d_out[0:131072] ----------------
__global__ __launch_bounds__(256) void final_kernel(const float* __restrict__ res_mid, const float* __restrict__ fc2_w,
                                                    const float* __restrict__ fc2_b, const float* __restrict__ points,
                                                    float* __restrict__ out) {
  int oid = blockIdx.x * 256 + threadIdx.x;
  int m = oid >> 5, c = oid & 31;
  float a = fc2_b[c];
  const float* rm = res_mid + m * 512;
  for (int kk = 0; kk < 512; ++kk) a = fmaf(rm[kk], fc2_w[kk * 32 + c], a);
  out[oid] = a + points[oid];
}

// ---------------- MFMA GEMM engine, BKT=32, counted-vmcnt dbuf pipeline ----------------
// LDS rows 64B; slot s' of row r holds global k-slot s'^((r>>1)&3)  ->  reads 2-way max (free).
// gld_lds: linear dest, pre-swizzled global source col. ds_write (dual A): swizzled LDS col.
// SRC: 0 = A from global bf16; 2 = h1 on the fly, dw1/db1 pre-staged in LDS (no per-iter global loads)
// EPI: 3 = softmax+res_mid; 4 = transposed bf16 (WpT); 5 = DUAL (pe f32 + h2 bf16);
//      6 = part-major bf16 (qkv); 7 = plain bf16 (qkg)
struct GP {
  const bf16_t* A; const bf16_t* Bt; const bf16_t* Bt2;
  bf16_t* Cb; float* Cf; const float* bias; int ldc;
  const float* xyz; const int* knn; const float* dw1; const float* db1;
  const float* cc; const bf16_t* qkg;
  const bf16_t* vb; float* pe_attn; float* res_mid;
};

template <int SRC, int EPI>
__global__ __launch_bounds__(256) void gemm_kernel(GP gp) {
  __shared__ bf16_t Alds[2 * BM * BKT];
  __shared__ bf16_t Blds[2 * BN * BKT];
  __shared__ bf16_t B2lds[(EPI == 5) ? (2 * BN * BKT) : 8];
  __shared__ float  wl[(SRC == 2) ? 4 * 512 : 8];
  int tid  = threadIdx.x;
  int lane = tid & 63, wave = tid >> 6;
  int wr = wave >> 1, wc = wave & 1;
  int lr = lane & 15, lg = lane >> 4;

  // XCD-aware bijective swizzle (nwg % 8 == 0 for all launches)
  int gx = gridDim.x;
  int nwg = gx * gridDim.y;
  int orig = blockIdx.y * gx + blockIdx.x;
  int cpx = nwg >> 3;
  int swz = (orig & 7) * cpx + (orig >> 3);
  int bx = swz % gx;
  int by = swz / gx;
  int n0 = bx * BN, m0 = by * BM;

  f32x4 acc[4][4];
  f32x4 acc2[(EPI == 5) ? 4 : 1][4];
  #pragma unroll
  for (int i = 0; i < 4; ++i)
    #pragma unroll
    for (int j = 0; j < 4; ++j) {
      acc[i][j] = (f32x4){0.f, 0.f, 0.f, 0.f};
      if (EPI == 5) acc2[i][j] = (f32x4){0.f, 0.f, 0.f, 0.f};
    }

  int rS2 = tid >> 2;                                    // 0..63 staging row (and +64)
  int sl  = tid & 3;                                     // natural k-slot for compute path
  int swb = (rS2 >> 1) & 3;                              // row-swizzle bits (same for rS2 and rS2+64)
  int scS = ((sl ^ swb) << 3);                           // pre-swizzled source col (elements)

  // dual: h1 weights into LDS once; per-thread delta for 2 staged rows
  float dx0, dy0, dz0, dx1, dy1, dz1;
  if (SRC == 2) {
    for (int c = tid; c < 512; c += 256) {
      wl[c]        = gp.dw1[c];
      wl[512 + c]  = gp.dw1[512 + c];
      wl[1024 + c] = gp.dw1[1024 + c];
      wl[1536 + c] = gp.db1[c];
    }
    int m_a = m0 + rS2, m_b = m0 + rS2 + 64;
    int ga = m_a >> 4, ja = gp.knn[m_a];
    int gb = m_b >> 4, jb = gp.knn[m_b];
    dx0 = gp.xyz[ga * 3 + 0] - gp.xyz[ja * 3 + 0];
    dy0 = gp.xyz[ga * 3 + 1] - gp.xyz[ja * 3 + 1];
    dz0 = gp.xyz[ga * 3 + 2] - gp.xyz[ja * 3 + 2];
    dx1 = gp.xyz[gb * 3 + 0] - gp.xyz[jb * 3 + 0];
    dy1 = gp.xyz[gb * 3 + 1] - gp.xyz[jb * 3 + 1];
    dz1 = gp.xyz[gb * 3 + 2] - gp.xyz[jb * 3 + 2];
    __syncthreads();   // wl ready (once; full drain OK here)
  }

  auto stageA = [&](int t, int buf) {
    int k0 = t * BKT;
    if (SRC == 0) {
      GLD_LDS16(gp.A + (size_t)(m0 + rS2) * 512 + k0 + scS,       Alds + buf * (BM * BKT) + tid * 8);
      GLD_LDS16(gp.A + (size_t)(m0 + 64 + rS2) * 512 + k0 + scS,  Alds + buf * (BM * BKT) + 2048 + tid * 8);
    } else {
      int cb = k0 + sl * 8;   // natural col base
      f32x4 w0a = *(const f32x4*)(&wl[cb]),        w0b = *(const f32x4*)(&wl[cb + 4]);
      f32x4 w1a = *(const f32x4*)(&wl[512 + cb]),  w1b = *(const f32x4*)(&wl[512 + cb + 4]);
      f32x4 w2a = *(const f32x4*)(&wl[1024 + cb]), w2b = *(const f32x4*)(&wl[1024 + cb + 4]);
      f32x4 bba = *(const f32x4*)(&wl[1536 + cb]), bbb = *(const f32x4*)(&wl[1536 + cb + 4]);
      bf16_t* Ab = Alds + buf * (BM * BKT);
      bf16x8 o;
      #pragma unroll
      for (int u = 0; u < 4; ++u) {
        float h = fmaf(dz0, w2a[u], fmaf(dy0, w1a[u], dx0 * w0a[u])) + bba[u];
        o[u] = (bf16_t)fmaxf(h, 0.0f);
      }
      #pragma unroll
      for (int u = 0; u < 4; ++u) {
        float h = fmaf(dz0, w2b[u], fmaf(dy0, w1b[u], dx0 * w0b[u])) + bbb[u];
        o[4 + u] = (bf16_t)fmaxf(h, 0.0f);
      }
      *(bf16x8*)(&Ab[rS2 * BKT + ((sl ^ swb) << 3)]) = o;
      #pragma unroll
      for (int u = 0; u < 4; ++u) {
        float h = fmaf(dz1, w2a[u], fmaf(dy1, w1a[u], dx1 * w0a[u])) + bba[u];
        o[u] = (bf16_t)fmaxf(h, 0.0f);
      }
      #pragma unroll
      for (int u = 0; u < 4; ++u) {
        float h = fmaf(dz1, w2b[u], fmaf(dy1, w1b[u], dx1 * w0b[u])) + bbb[u];
        o[4 + u] = (bf16_t)fmaxf(h, 0.0f);
      }
      *(bf16x8*)(&Ab[(rS2 + 64) * BKT + ((sl ^ swb) << 3)]) = o;
    }
  };
  auto stageB = [&](int t, int buf) {
    int k0 = t * BKT;
    GLD_LDS16(gp.Bt + (size_t)(n0 + rS2) * 512 + k0 + scS,       Blds + buf * (BN * BKT) + tid * 8);
    GLD_LDS16(gp.Bt + (size_t)(n0 + 64 + rS2) * 512 + k0 + scS,  Blds + buf * (BN * BKT) + 2048 + tid * 8);
    if (EPI == 5) {
      GLD_LDS16(gp.Bt2 + (size_t)(n0 + rS2) * 512 + k0 + scS,      B2lds + buf * (BN * BKT) + tid * 8);
      GLD_LDS16(gp.Bt2 + (size_t)(n0 + 64 + rS2) * 512 + k0 + scS, B2lds + buf * (BN * BKT) + 2048 + tid * 8);
    }
  };

  stageA(0, 0);
  stageB(0, 0);

  #pragma unroll 1
  for (int t = 0; t < NT; ++t) {
    int cur = t & 1;
    if (t + 1 < NT) {
      stageA(t + 1, cur ^ 1);
      stageB(t + 1, cur ^ 1);
      // drain stage t only; stage t+1's vm loads stay in flight across the barrier
      if (SRC == 0) {
        if (EPI == 5) asm volatile("s_waitcnt vmcnt(6)" ::: "memory");
        else          asm volatile("s_waitcnt vmcnt(4)" ::: "memory");
      } else {
        if (EPI == 5) asm volatile("s_waitcnt vmcnt(4) lgkmcnt(0)" ::: "memory");
        else          asm volatile("s_waitcnt vmcnt(2) lgkmcnt(0)" ::: "memory");
      }
    } else {
      asm volatile("s_waitcnt vmcnt(0) lgkmcnt(0)" ::: "memory");
    }
    __builtin_amdgcn_s_barrier();     // buf[cur] ready

    const bf16_t* Ab = Alds + cur * (BM * BKT);
    const bf16_t* Bb = Blds + cur * (BN * BKT);
    const bf16_t* B2b = B2lds + cur * (BN * BKT);
    bf16x8 af[4], bfr[4], b2r[4];
    #pragma unroll
    for (int mi = 0; mi < 4; ++mi) {
      int rr = wr * 64 + mi * 16 + lr;
      af[mi] = *(const bf16x8*)(&Ab[rr * BKT + ((lg ^ ((rr >> 1) & 3)) << 3)]);
    }
    #pragma unroll
    for (int nj = 0; nj < 4; ++nj) {
      int rr = wc * 64 + nj * 16 + lr;
      bfr[nj] = *(const bf16x8*)(&Bb[rr * BKT + ((lg ^ ((rr >> 1) & 3)) << 3)]);
      if (EPI == 5) b2r[nj] = *(const bf16x8*)(&B2b[rr * BKT + ((lg ^ ((rr >> 1) & 3)) << 3)]);
    }
    #pragma unroll
    for (int mi = 0; mi < 4; ++mi)
      #pragma unroll
      for (int nj = 0; nj < 4; ++nj) {
        acc[mi][nj] = __builtin_amdgcn_mfma_f32_16x16x32_bf16(af[mi], bfr[nj], acc[mi][nj], 0, 0, 0);
        if (EPI == 5)
          acc2[mi][nj] = __builtin_amdgcn_mfma_f32_16x16x32_bf16(af[mi], b2r[nj], acc2[mi][nj], 0, 0, 0);
      }
    __builtin_amdgcn_s_barrier();     // all waves done reading buf[cur]
  }

  if (EPI == 4) {
    #pragma unroll
    for (int mi = 0; mi < 4; ++mi)
      #pragma unroll
      for (int nj = 0; nj < 4; ++nj) {
        int col = n0 + wc * 64 + nj * 16 + lr;
        #pragma unroll
        for (int r = 0; r < 4; ++r) {
          int row = m0 + wr * 64 + mi * 16 + lg * 4 + r;
          gp.Cb[(size_t)col * 512 + row] = (bf16_t)acc[mi][nj][r];
        }
      }
  } else if (EPI == 6) {
    #pragma unroll
    for (int mi = 0; mi < 4; ++mi)
      #pragma unroll
      for (int nj = 0; nj < 4; ++nj) {
        int col = n0 + wc * 64 + nj * 16 + lr;
        int part = col >> 9, c = col & 511;
        #pragma unroll
        for (int r = 0; r < 4; ++r) {
          int row = m0 + wr * 64 + mi * 16 + lg * 4 + r;
          gp.Cb[((size_t)part * 4096 + row) * 512 + c] = (bf16_t)acc[mi][nj][r];
        }
      }
  } else if (EPI == 7) {
    #pragma unroll
    for (int mi = 0; mi < 4; ++mi)
      #pragma unroll
      for (int nj = 0; nj < 4; ++nj) {
        int col = n0 + wc * 64 + nj * 16 + lr;
        #pragma unroll
        for (int r = 0; r < 4; ++r) {
          int row = m0 + wr * 64 + mi * 16 + lg * 4 + r;
          gp.Cb[(size_t)row * gp.ldc + col] = (bf16_t)acc[mi][nj][r];
        }
      }
  } else if (EPI == 5) {
    // DUAL: pe = acc + db2 -> f32 (attn region, overwritten later by attn);
    //       h2 = relu(acc2 + cc + qg - kg) -> bf16
    #pragma unroll
    for (int mi = 0; mi < 4; ++mi) {
      int g = (m0 + wr * 64 + mi * 16) >> 4;
      #pragma unroll
      for (int nj = 0; nj < 4; ++nj) {
        int col = n0 + wc * 64 + nj * 16 + lr;
        float db2v = gp.bias[col];
        float ccv  = gp.cc[col];
        float qgv  = (float)gp.qkg[(size_t)g * 512 + col];
        #pragma unroll
        for (int r = 0; r < 4; ++r) {
          int row = m0 + wr * 64 + mi * 16 + lg * 4 + r;
          gp.Cf[(size_t)row * 512 + col] = acc[mi][nj][r] + db2v;
          int j = gp.knn[row];
          float kgv = (float)gp.qkg[(size_t)(4096 + j) * 512 + col];
          float hv = acc2[mi][nj][r] + ccv + qgv - kgv;
          gp.Cb[(size_t)row * 512 + col] = (bf16_t)fmaxf(hv, 0.0f);
        }
      }
    }
  } else {
    // EPI == 3: softmax over neighbors; each 16x16 acc tile = one 16-slot group
    const float scale = 22.62741699796952f;   // float(np.sqrt(512))
    #pragma unroll
    for (int mi = 0; mi < 4; ++mi) {
      int g = (m0 + wr * 64 + mi * 16) >> 4;
      #pragma unroll
      for (int nj = 0; nj < 4; ++nj) {
        int col = n0 + wc * 64 + nj * 16 + lr;
        float sv[4];
        float mx = -INFINITY;
        #pragma unroll
        for (int r = 0; r < 4; ++r) {
          sv[r] = (acc[mi][nj][r] + gp.bias[col]) / scale;
          mx = fmaxf(mx, sv[r]);
        }
        mx = fmaxf(mx, __shfl_xor(mx, 16));
        mx = fmaxf(mx, __shfl_xor(mx, 32));
        float e[4], sum = 0.f;
        #pragma unroll
        for (int r = 0; r < 4; ++r) { e[r] = expf(sv[r] - mx); sum += e[r]; }
        sum += __shfl_xor(sum, 16);
        sum += __shfl_xor(sum, 32);
        float part = 0.f;
        #pragma unroll
        for (int r = 0; r < 4; ++r) {
          int row = g * 16 + lg * 4 + r;
          float at = e[r] / sum;
          int j = gp.knn[row];
          float vv  = (float)gp.vb[(size_t)j * 512 + col];
          float pev = gp.pe_attn[(size_t)row * 512 + col];   // read pe BEFORE overwriting (same lane)
          part = fmaf(at, vv + pev, part);
          gp.pe_attn[(size_t)row * 512 + col] = at;
        }
        part += __shfl_xor(part, 16);
        part += __shfl_xor(part, 32);
        if (lg == 0) gp.res_mid[(size_t)g * 512 + col] = part;
      }
    }
  }
}

extern "C" void kernel_launch(void* const* d_in, const int* in_sizes, int n_in,
                              void* d_out, int out_size, void* d_ws, size_t ws_size,
                              hipStream_t stream) {
  const float* xyz    = (const float*)d_in[0];
  const float* points = (const float*)d_in[1];
  const float* fc1_w  = (const float*)d_in[2];
  const float* fc1_b  = (const float*)d_in[3];
  const float* fc2_w  = (const float*)d_in[4];
  const float* fc2_b  = (const float*)d_in[5];
  const float* dw1    = (const float*)d_in[6];
  const float* db1    = (const float*)d_in[7];
  const float* dw2    = (const float*)d_in[8];
  const float* db2    = (const float*)d_in[9];
  const float* gw1    = (const float*)d_in[10];
  const float* gb1    = (const float*)d_in[11];
  const float* gw2    = (const float*)d_in[12];
  const float* gb2    = (const float*)d_in[13];
  const float* wq     = (const float*)d_in[14];
  const float* wk     = (const float*)d_in[15];
  const float* wv     = (const float*)d_in[16];

  float* out = (float*)d_out;
  float* attn_pe = out + 131072;   // [65536][512] f32: pe, overwritten in-place by attn

  char* w = (char*)d_ws;
  bf16_t* wqkvT  = (bf16_t*)w; w += (size_t)1536 * 512 * 2;
  bf16_t* dw2T   = (bf16_t*)w; w += (size_t)512 * 512 * 2;
  bf16_t* gw1T   = (bf16_t*)w; w += (size_t)512 * 512 * 2;
  bf16_t* gw2T   = (bf16_t*)w; w += (size_t)512 * 512 * 2;
  bf16_t* dw2b   = (bf16_t*)w; w += (size_t)512 * 512 * 2;
  bf16_t* WpT    = (bf16_t*)w; w += (size_t)512 * 512 * 2;
  float*  cc     = (float*)w;  w += (size_t)512 * 4;
  int*    knn    = (int*)w;    w += (size_t)65536 * 4;
  bf16_t* xb     = (bf16_t*)w; w += (size_t)4096 * 512 * 2;
  bf16_t* qkvb   = (bf16_t*)w; w += (size_t)3 * 4096 * 512 * 2;  // part-major: q,k,v
  bf16_t* qkg    = (bf16_t*)w; w += (size_t)2 * 4096 * 512 * 2;  // q@gw1, k@gw1
  bf16_t* h2     = (bf16_t*)w; w += (size_t)65536 * 512 * 2;
  float*  res_mid= (float*)w;  w += (size_t)4096 * 512 * 4;

  TC7 tc;
  tc.src[0] = wq;  tc.dst[0] = wqkvT;
  tc.src[1] = wk;  tc.dst[1] = wqkvT + 512 * 512;
  tc.src[2] = wv;  tc.dst[2] = wqkvT + 2 * 512 * 512;
  tc.src[3] = dw2; tc.dst[3] = dw2T;
  tc.src[4] = gw1; tc.dst[4] = gw1T;
  tc.src[5] = gw2; tc.dst[5] = gw2T;
  tc.src[6] = dw2; tc.dst[6] = dw2b;
  tcast7_kernel<<<7168, 256, 0, stream>>>(tc);

  knn_kernel<<<1024, 256, 0, stream>>>(xyz, knn);
  xfeat_kernel<<<4096, 256, 0, stream>>>(points, fc1_w, fc1_b, xb);
  cc_kernel<<<2, 256, 0, stream>>>(db2, gw1, gb1, cc);

  // Wp = dw2 @ gw1 -> WpT (Bt-format)
  GP gp{};
  gp.A = dw2b; gp.Bt = gw1T; gp.Cb = WpT; gp.ldc = 512;
  gemm_kernel<0, 4><<<dim3(4, 4), 256, 0, stream>>>(gp);

  // qkv = x @ [wq|wk|wv] -> part-major bf16
  GP gq{};
  gq.A = xb; gq.Bt = wqkvT; gq.Cb = qkvb; gq.ldc = 1536;
  gemm_kernel<0, 6><<<dim3(12, 32), 256, 0, stream>>>(gq);

  // [q;k] @ gw1 -> qkg
  GP gk{};
  gk.A = qkvb; gk.Bt = gw1T; gk.Cb = qkg; gk.ldc = 512;
  gemm_kernel<0, 7><<<dim3(4, 64), 256, 0, stream>>>(gk);

  // DUAL: A = h1 on the fly (dw1/db1 in LDS); pe = A@dw2T + db2 -> f32 attn region;
  //       h2 = relu(A@WpT + cc + qg - kg) -> bf16
  GP gd{};
  gd.Bt = dw2T; gd.Bt2 = WpT; gd.Cf = attn_pe; gd.Cb = h2; gd.bias = db2;
  gd.xyz = xyz; gd.knn = knn; gd.dw1 = dw1; gd.db1 = db1;
  gd.cc = cc; gd.qkg = qkg;
  gemm_kernel<2, 5><<<dim3(4, 512), 256, 0, stream>>>(gd);

  // gamma2 + softmax: a2 = h2 @ gw2 + gb2; attn in-place over pe; res_mid = sum attn*(v+pe)
  GP gs{};
  gs.A = h2; gs.Bt = gw2T; gs.bias = gb2;
  gs.knn = knn; gs.vb = qkvb + (size_t)2 * 4096 * 512; gs.pe_attn = attn_pe; gs.res_mid = res_mid;
  gemm_kernel<0, 3><<<dim3(4, 512), 256, 0, stream>>>(gs);

  final_kernel<<<512, 256, 0, stream>>>(res_mid, fc2_w, fc2_b, points, out);
}

// Round 8
// 501.250 us; speedup vs baseline: 1.0072x; 1.0072x over previous
//
#include <hip/hip_runtime.h>
#include <hip/hip_bf16.h>
#include <math.h>

typedef __bf16 bf16_t;
typedef float f32x4 __attribute__((ext_vector_type(4)));
typedef bf16_t bf16x8 __attribute__((ext_vector_type(8)));

#define BM 128
#define BN 128
#define BKT 32
#define NT 16    // 512 / BKT

// async global->LDS, 16B per lane; LDS dest = wave-uniform base + lane*16 (linear)
#define GLD_LDS16(gp, lp) __builtin_amdgcn_global_load_lds( \
    (const __attribute__((address_space(1))) void*)(gp), \
    (__attribute__((address_space(3))) void*)(lp), 16, 0, 0)

// ---------------- weight prep: jobs 0..3 transpose+cast, jobs 4..6 plain cast ----------------
// 0: wv^T -> wBig[0:512); 1: dw2^T; 2: gw1^T; 3: gw2^T; 4: dw2 plain; 5: wq plain; 6: wk plain
struct TC7 { const float* src[7]; bf16_t* dst[7]; };
__global__ __launch_bounds__(256) void tcast7_kernel(TC7 tc) {
  int job = blockIdx.x >> 10;
  int idx = (blockIdx.x & 1023) * 256 + threadIdx.x;
  if (job < 4) {
    int n = idx >> 9, k = idx & 511;
    tc.dst[job][idx] = (bf16_t)tc.src[job][k * 512 + n];
  } else {
    tc.dst[job][idx] = (bf16_t)tc.src[job][idx];
  }
}

// ---------------- cc[n] = sum_d db2[d]*gw1[d][n] + gb1[n] ----------------
__global__ __launch_bounds__(256) void cc_kernel(const float* __restrict__ db2, const float* __restrict__ gw1,
                                                 const float* __restrict__ gb1, float* __restrict__ cc) {
  int n = blockIdx.x * 256 + threadIdx.x;
  float s = gb1[n];
  for (int d = 0; d < 512; ++d) s = fmaf(db2[d], gw1[d * 512 + n], s);
  cc[n] = s;
}

// ---------------- KNN: one WAVE per query; per-lane u64 keys in registers ----------------
__global__ __launch_bounds__(256) void knn_kernel(const float* __restrict__ xyz, int* __restrict__ knn) {
  __shared__ float sx[2048], sy[2048], sz[2048], sq[2048];
  int tid = threadIdx.x;
  int lane = tid & 63, wave = tid >> 6;
  int gq = blockIdx.x * 4 + wave;
  int b  = gq >> 11;
  int base = b << 11;
  for (int p = tid; p < 2048; p += 256) {
    float x = xyz[(base + p) * 3 + 0];
    float y = xyz[(base + p) * 3 + 1];
    float z = xyz[(base + p) * 3 + 2];
    sx[p] = x; sy[p] = y; sz[p] = z;
    sq[p] = __fadd_rn(__fadd_rn(__fmul_rn(x, x), __fmul_rn(y, y)), __fmul_rn(z, z));
  }
  __syncthreads();
  int iq = gq & 2047;
  float qx = sx[iq], qy = sy[iq], qz = sz[iq], sqi = sq[iq];

  unsigned long long key[32];
  #pragma unroll
  for (int j = 0; j < 32; ++j) {
    int p = lane + j * 64;
    float d = __fmul_rn(sx[p], qx);
    d = fmaf(sy[p], qy, d);
    d = fmaf(sz[p], qz, d);
    float dist = __fsub_rn(__fadd_rn(sqi, sq[p]), __fmul_rn(2.0f, d));
    unsigned int bits = __float_as_uint(dist);
    unsigned int sk = bits ^ (unsigned int)(((int)bits >> 31) | 0x80000000);
    key[j] = ((unsigned long long)sk << 32) | (unsigned int)p;
  }

  int r = 0;
  #pragma unroll 1
  for (int s = 0; s < 16; ++s) {
    unsigned long long m = key[0];
    #pragma unroll
    for (int j = 1; j < 32; ++j) m = (key[j] < m) ? key[j] : m;
    #pragma unroll
    for (int off = 32; off > 0; off >>= 1) {
      unsigned long long o = (unsigned long long)__shfl_xor((long long)m, off);
      if (o < m) m = o;
    }
    if (lane == s) r = base + (int)(m & 0xFFFFFFFFu);
    #pragma unroll
    for (int j = 0; j < 32; ++j) key[j] = (key[j] == m) ? ~0ULL : key[j];
  }
  if (lane < 16) knn[gq * 16 + lane] = r;
}

// ---------------- x = points @ fc1_w + fc1_b -> bf16 [4096][512] ----------------
__global__ __launch_bounds__(256) void xfeat_kernel(const float* __restrict__ points, const float* __restrict__ fc1_w,
                                                    const float* __restrict__ fc1_b, bf16_t* __restrict__ xb) {
  __shared__ float p[32];
  int m = blockIdx.x, tid = threadIdx.x;
  if (tid < 32) p[tid] = points[m * 32 + tid];
  __syncthreads();
  for (int c = tid; c < 512; c += 256) {
    float a = fc1_b[c];
    #pragma unroll
    for (int kk = 0; kk < 32; ++kk) a = fmaf(p[kk], fc1_w[kk * 512 + c], a);
    xb[m * 512 + c] = (bf16_t)a;
  }
}

// ---------------- res = res_mid @ fc2_w + fc2_b + points -> d_out[0:131072] ----------------
__global__ __launch_bounds__(256) void final_kernel(const float* __restrict__ res_mid, const float* __restrict__ fc2_w,
                                                    const float* __restrict__ fc2_b, const float* __restrict__ points,
                                                    float* __restrict__ out) {
  int oid = blockIdx.x * 256 + threadIdx.x;
  int m = oid >> 5, c = oid & 31;
  float a = fc2_b[c];
  const float* rm = res_mid + m * 512;
  for (int kk = 0; kk < 512; ++kk) a = fmaf(rm[kk], fc2_w[kk * 32 + c], a);
  out[oid] = a + points[oid];
}

// ---------------- MFMA GEMM engine, BKT=32, counted-vmcnt dbuf pipeline ----------------
// LDS rows 64B; slot s' of row r holds global k-slot s'^((r>>1)&3) -> reads 2-way max (free).
// SRC: 0 = A from global bf16 (gld_lds); 2 = h1 on the fly (dw1/db1 in LDS), A-stage AFTER the
//      MFMA phase so its VALU hides under the MFMA drain (T14) + setprio (T5).
// EPI: 3 = softmax over 16-row groups + res_mid; 4 = transposed bf16 store w/ job-select (weight prods);
//      5 = DUAL (pe f32 -> attn region + h2 bf16); 6 = part-major bf16 (v|qg|kg)
struct GP {
  const bf16_t* A; const bf16_t* Bt; const bf16_t* Bt2;
  bf16_t* Cb; float* Cf; const float* bias; int ldc;
  const float* xyz; const int* knn; const float* dw1; const float* db1;
  const float* cc; const bf16_t* qkg;
  const bf16_t* vb; float* pe_attn; float* res_mid;
  const bf16_t* Aj[3]; bf16_t* Cbj[3];
};

template <int SRC, int EPI>
__global__ __launch_bounds__(256) void gemm_kernel(GP gp) {
  __shared__ bf16_t Alds[2 * BM * BKT];
  __shared__ bf16_t Blds[2 * BN * BKT];
  __shared__ bf16_t B2lds[(EPI == 5) ? (2 * BN * BKT) : 8];
  __shared__ float  wl[(SRC == 2) ? 4 * 512 : 8];
  int tid  = threadIdx.x;
  int lane = tid & 63, wave = tid >> 6;
  int wr = wave >> 1, wc = wave & 1;
  int lr = lane & 15, lg = lane >> 4;

  // XCD-aware bijective swizzle (nwg % 8 == 0 for all launches)
  int gx = gridDim.x;
  int nwg = gx * gridDim.y;
  int orig = blockIdx.y * gx + blockIdx.x;
  int cpx = nwg >> 3;
  int swz = (orig & 7) * cpx + (orig >> 3);
  int bx = swz % gx;
  int by = swz / gx;
  int n0 = bx * BN;
  int m0 = ((EPI == 4) ? (by & 3) : by) * BM;
  const bf16_t* Aptr = (EPI == 4) ? gp.Aj[by >> 2] : gp.A;

  f32x4 acc[4][4];
  f32x4 acc2[(EPI == 5) ? 4 : 1][4];
  #pragma unroll
  for (int i = 0; i < 4; ++i)
    #pragma unroll
    for (int j = 0; j < 4; ++j) {
      acc[i][j] = (f32x4){0.f, 0.f, 0.f, 0.f};
      if (EPI == 5) acc2[i][j] = (f32x4){0.f, 0.f, 0.f, 0.f};
    }

  int rS2 = tid >> 2;                                    // 0..63 staging row (and +64)
  int sl  = tid & 3;                                     // natural k-slot
  int swb = (rS2 >> 1) & 3;                              // row-swizzle bits
  int scS = ((sl ^ swb) << 3);                           // pre-swizzled source col (elements)

  float dx0, dy0, dz0, dx1, dy1, dz1;
  if (SRC == 2) {
    for (int c = tid; c < 512; c += 256) {
      wl[c]        = gp.dw1[c];
      wl[512 + c]  = gp.dw1[512 + c];
      wl[1024 + c] = gp.dw1[1024 + c];
      wl[1536 + c] = gp.db1[c];
    }
    int m_a = m0 + rS2, m_b = m0 + rS2 + 64;
    int ga = m_a >> 4, ja = gp.knn[m_a];
    int gb = m_b >> 4, jb = gp.knn[m_b];
    dx0 = gp.xyz[ga * 3 + 0] - gp.xyz[ja * 3 + 0];
    dy0 = gp.xyz[ga * 3 + 1] - gp.xyz[ja * 3 + 1];
    dz0 = gp.xyz[ga * 3 + 2] - gp.xyz[ja * 3 + 2];
    dx1 = gp.xyz[gb * 3 + 0] - gp.xyz[jb * 3 + 0];
    dy1 = gp.xyz[gb * 3 + 1] - gp.xyz[jb * 3 + 1];
    dz1 = gp.xyz[gb * 3 + 2] - gp.xyz[jb * 3 + 2];
    __syncthreads();   // wl ready (once)
  }

  auto stageA = [&](int t, int buf) {
    int k0 = t * BKT;
    if (SRC == 0) {
      GLD_LDS16(Aptr + (size_t)(m0 + rS2) * 512 + k0 + scS,       Alds + buf * (BM * BKT) + tid * 8);
      GLD_LDS16(Aptr + (size_t)(m0 + 64 + rS2) * 512 + k0 + scS,  Alds + buf * (BM * BKT) + 2048 + tid * 8);
    } else {
      int cb = k0 + sl * 8;
      f32x4 w0a = *(const f32x4*)(&wl[cb]),        w0b = *(const f32x4*)(&wl[cb + 4]);
      f32x4 w1a = *(const f32x4*)(&wl[512 + cb]),  w1b = *(const f32x4*)(&wl[512 + cb + 4]);
      f32x4 w2a = *(const f32x4*)(&wl[1024 + cb]), w2b = *(const f32x4*)(&wl[1024 + cb + 4]);
      f32x4 bba = *(const f32x4*)(&wl[1536 + cb]), bbb = *(const f32x4*)(&wl[1536 + cb + 4]);
      bf16_t* Ab = Alds + buf * (BM * BKT);
      bf16x8 o;
      #pragma unroll
      for (int u = 0; u < 4; ++u) {
        float h = fmaf(dz0, w2a[u], fmaf(dy0, w1a[u], dx0 * w0a[u])) + bba[u];
        o[u] = (bf16_t)fmaxf(h, 0.0f);
      }
      #pragma unroll
      for (int u = 0; u < 4; ++u) {
        float h = fmaf(dz0, w2b[u], fmaf(dy0, w1b[u], dx0 * w0b[u])) + bbb[u];
        o[4 + u] = (bf16_t)fmaxf(h, 0.0f);
      }
      *(bf16x8*)(&Ab[rS2 * BKT + ((sl ^ swb) << 3)]) = o;
      #pragma unroll
      for (int u = 0; u < 4; ++u) {
        float h = fmaf(dz1, w2a[u], fmaf(dy1, w1a[u], dx1 * w0a[u])) + bba[u];
        o[u] = (bf16_t)fmaxf(h, 0.0f);
      }
      #pragma unroll
      for (int u = 0; u < 4; ++u) {
        float h = fmaf(dz1, w2b[u], fmaf(dy1, w1b[u], dx1 * w0b[u])) + bbb[u];
        o[4 + u] = (bf16_t)fmaxf(h, 0.0f);
      }
      *(bf16x8*)(&Ab[(rS2 + 64) * BKT + ((sl ^ swb) << 3)]) = o;
    }
  };
  auto stageB = [&](int t, int buf) {
    int k0 = t * BKT;
    GLD_LDS16(gp.Bt + (size_t)(n0 + rS2) * 512 + k0 + scS,       Blds + buf * (BN * BKT) + tid * 8);
    GLD_LDS16(gp.Bt + (size_t)(n0 + 64 + rS2) * 512 + k0 + scS,  Blds + buf * (BN * BKT) + 2048 + tid * 8);
    if (EPI == 5) {
      GLD_LDS16(gp.Bt2 + (size_t)(n0 + rS2) * 512 + k0 + scS,      B2lds + buf * (BN * BKT) + tid * 8);
      GLD_LDS16(gp.Bt2 + (size_t)(n0 + 64 + rS2) * 512 + k0 + scS, B2lds + buf * (BN * BKT) + 2048 + tid * 8);
    }
  };
  auto mfmaPhase = [&](int cur) {
    const bf16_t* Ab = Alds + cur * (BM * BKT);
    const bf16_t* Bb = Blds + cur * (BN * BKT);
    const bf16_t* B2b = B2lds + cur * (BN * BKT);
    bf16x8 af[4], bfr[4], b2r[4];
    #pragma unroll
    for (int mi = 0; mi < 4; ++mi) {
      int rr = wr * 64 + mi * 16 + lr;
      af[mi] = *(const bf16x8*)(&Ab[rr * BKT + ((lg ^ ((rr >> 1) & 3)) << 3)]);
    }
    #pragma unroll
    for (int nj = 0; nj < 4; ++nj) {
      int rr = wc * 64 + nj * 16 + lr;
      bfr[nj] = *(const bf16x8*)(&Bb[rr * BKT + ((lg ^ ((rr >> 1) & 3)) << 3)]);
      if (EPI == 5) b2r[nj] = *(const bf16x8*)(&B2b[rr * BKT + ((lg ^ ((rr >> 1) & 3)) << 3)]);
    }
    #pragma unroll
    for (int mi = 0; mi < 4; ++mi)
      #pragma unroll
      for (int nj = 0; nj < 4; ++nj) {
        acc[mi][nj] = __builtin_amdgcn_mfma_f32_16x16x32_bf16(af[mi], bfr[nj], acc[mi][nj], 0, 0, 0);
        if (EPI == 5)
          acc2[mi][nj] = __builtin_amdgcn_mfma_f32_16x16x32_bf16(af[mi], b2r[nj], acc2[mi][nj], 0, 0, 0);
      }
  };

  stageA(0, 0);
  stageB(0, 0);

  #pragma unroll 1
  for (int t = 0; t < NT; ++t) {
    int cur = t & 1;
    if (SRC == 0) {
      if (t + 1 < NT) {
        stageA(t + 1, cur ^ 1);
        stageB(t + 1, cur ^ 1);
        asm volatile("s_waitcnt vmcnt(4)" ::: "memory");
      } else {
        asm volatile("s_waitcnt vmcnt(0)" ::: "memory");
      }
      __builtin_amdgcn_s_barrier();
      mfmaPhase(cur);
      __builtin_amdgcn_s_barrier();
    } else {
      // dual: B-prefetch async before barrier; A-stage (h1 VALU) AFTER the MFMA phase
      if (t + 1 < NT) {
        stageB(t + 1, cur ^ 1);
        asm volatile("s_waitcnt vmcnt(4) lgkmcnt(0)" ::: "memory");
      } else {
        asm volatile("s_waitcnt vmcnt(0) lgkmcnt(0)" ::: "memory");
      }
      __builtin_amdgcn_s_barrier();
      __builtin_amdgcn_s_setprio(1);
      mfmaPhase(cur);
      __builtin_amdgcn_s_setprio(0);
      if (t + 1 < NT) stageA(t + 1, cur ^ 1);
      __builtin_amdgcn_s_barrier();
    }
  }

  if (EPI == 4) {
    bf16_t* CbT = gp.Cbj[by >> 2];
    #pragma unroll
    for (int mi = 0; mi < 4; ++mi)
      #pragma unroll
      for (int nj = 0; nj < 4; ++nj) {
        int col = n0 + wc * 64 + nj * 16 + lr;
        #pragma unroll
        for (int r = 0; r < 4; ++r) {
          int row = m0 + wr * 64 + mi * 16 + lg * 4 + r;
          CbT[(size_t)col * 512 + row] = (bf16_t)acc[mi][nj][r];
        }
      }
  } else if (EPI == 6) {
    #pragma unroll
    for (int mi = 0; mi < 4; ++mi)
      #pragma unroll
      for (int nj = 0; nj < 4; ++nj) {
        int col = n0 + wc * 64 + nj * 16 + lr;
        int part = col >> 9, c = col & 511;
        #pragma unroll
        for (int r = 0; r < 4; ++r) {
          int row = m0 + wr * 64 + mi * 16 + lg * 4 + r;
          gp.Cb[((size_t)part * 4096 + row) * 512 + c] = (bf16_t)acc[mi][nj][r];
        }
      }
  } else if (EPI == 5) {
    // DUAL: pe = acc + db2 -> f32 (attn region, overwritten later by g2); h2 = relu(acc2+cc+qg-kg)
    #pragma unroll
    for (int mi = 0; mi < 4; ++mi) {
      int g = (m0 + wr * 64 + mi * 16) >> 4;
      #pragma unroll
      for (int nj = 0; nj < 4; ++nj) {
        int col = n0 + wc * 64 + nj * 16 + lr;
        float db2v = gp.bias[col];
        float ccv  = gp.cc[col];
        float qgv  = (float)gp.qkg[((size_t)4096 + g) * 512 + col];        // part1 = qg
        #pragma unroll
        for (int r = 0; r < 4; ++r) {
          int row = m0 + wr * 64 + mi * 16 + lg * 4 + r;
          gp.Cf[(size_t)row * 512 + col] = acc[mi][nj][r] + db2v;
          int j = gp.knn[row];
          float kgv = (float)gp.qkg[((size_t)2 * 4096 + j) * 512 + col];   // part2 = kg
          float hv = acc2[mi][nj][r] + ccv + qgv - kgv;
          gp.Cb[(size_t)row * 512 + col] = (bf16_t)fmaxf(hv, 0.0f);
        }
      }
    }
  } else {
    // EPI == 3: softmax over neighbors; each 16x16 acc tile = one 16-slot group
    const float scale = 22.62741699796952f;   // float(np.sqrt(512))
    #pragma unroll
    for (int mi = 0; mi < 4; ++mi) {
      int g = (m0 + wr * 64 + mi * 16) >> 4;
      #pragma unroll
      for (int nj = 0; nj < 4; ++nj) {
        int col = n0 + wc * 64 + nj * 16 + lr;
        float sv[4];
        float mx = -INFINITY;
        #pragma unroll
        for (int r = 0; r < 4; ++r) {
          sv[r] = (acc[mi][nj][r] + gp.bias[col]) / scale;
          mx = fmaxf(mx, sv[r]);
        }
        mx = fmaxf(mx, __shfl_xor(mx, 16));
        mx = fmaxf(mx, __shfl_xor(mx, 32));
        float e[4], sum = 0.f;
        #pragma unroll
        for (int r = 0; r < 4; ++r) { e[r] = expf(sv[r] - mx); sum += e[r]; }
        sum += __shfl_xor(sum, 16);
        sum += __shfl_xor(sum, 32);
        float part = 0.f;
        #pragma unroll
        for (int r = 0; r < 4; ++r) {
          int row = g * 16 + lg * 4 + r;
          float at = e[r] / sum;
          int j = gp.knn[row];
          float vv  = (float)gp.vb[(size_t)j * 512 + col];                 // part0 = v
          float pev = gp.pe_attn[(size_t)row * 512 + col];   // read pe BEFORE overwriting (same lane)
          part = fmaf(at, vv + pev, part);
          gp.pe_attn[(size_t)row * 512 + col] = at;
        }
        part += __shfl_xor(part, 16);
        part += __shfl_xor(part, 32);
        if (lg == 0) gp.res_mid[(size_t)g * 512 + col] = part;
      }
    }
  }
}

extern "C" void kernel_launch(void* const* d_in, const int* in_sizes, int n_in,
                              void* d_out, int out_size, void* d_ws, size_t ws_size,
                              hipStream_t stream) {
  const float* xyz    = (const float*)d_in[0];
  const float* points = (const float*)d_in[1];
  const float* fc1_w  = (const float*)d_in[2];
  const float* fc1_b  = (const float*)d_in[3];
  const float* fc2_w  = (const float*)d_in[4];
  const float* fc2_b  = (const float*)d_in[5];
  const float* dw1    = (const float*)d_in[6];
  const float* db1    = (const float*)d_in[7];
  const float* dw2    = (const float*)d_in[8];
  const float* db2    = (const float*)d_in[9];
  const float* gw1    = (const float*)d_in[10];
  const float* gb1    = (const float*)d_in[11];
  const float* gw2    = (const float*)d_in[12];
  const float* gb2    = (const float*)d_in[13];
  const float* wq     = (const float*)d_in[14];
  const float* wk     = (const float*)d_in[15];
  const float* wv     = (const float*)d_in[16];

  float* out = (float*)d_out;
  float* attn_pe = out + 131072;   // [65536][512] f32: pe, overwritten in-place by attn

  char* w = (char*)d_ws;
  bf16_t* wBig   = (bf16_t*)w; w += (size_t)1536 * 512 * 2;   // [wv^T | Wqg^T | Wkg^T]
  bf16_t* dw2T   = (bf16_t*)w; w += (size_t)512 * 512 * 2;
  bf16_t* gw1T   = (bf16_t*)w; w += (size_t)512 * 512 * 2;
  bf16_t* gw2T   = (bf16_t*)w; w += (size_t)512 * 512 * 2;
  bf16_t* dw2b   = (bf16_t*)w; w += (size_t)512 * 512 * 2;
  bf16_t* wqb    = (bf16_t*)w; w += (size_t)512 * 512 * 2;
  bf16_t* wkb    = (bf16_t*)w; w += (size_t)512 * 512 * 2;
  bf16_t* WpT    = (bf16_t*)w; w += (size_t)512 * 512 * 2;
  float*  cc     = (float*)w;  w += (size_t)512 * 4;
  int*    knn    = (int*)w;    w += (size_t)65536 * 4;
  bf16_t* xb     = (bf16_t*)w; w += (size_t)4096 * 512 * 2;
  bf16_t* vqkg   = (bf16_t*)w; w += (size_t)3 * 4096 * 512 * 2;  // part-major: v, qg, kg
  bf16_t* h2     = (bf16_t*)w; w += (size_t)65536 * 512 * 2;
  float*  res_mid= (float*)w;  w += (size_t)4096 * 512 * 4;

  TC7 tc;
  tc.src[0] = wv;  tc.dst[0] = wBig;           // wv^T
  tc.src[1] = dw2; tc.dst[1] = dw2T;
  tc.src[2] = gw1; tc.dst[2] = gw1T;
  tc.src[3] = gw2; tc.dst[3] = gw2T;
  tc.src[4] = dw2; tc.dst[4] = dw2b;
  tc.src[5] = wq;  tc.dst[5] = wqb;
  tc.src[6] = wk;  tc.dst[6] = wkb;
  tcast7_kernel<<<7168, 256, 0, stream>>>(tc);

  knn_kernel<<<1024, 256, 0, stream>>>(xyz, knn);
  xfeat_kernel<<<4096, 256, 0, stream>>>(points, fc1_w, fc1_b, xb);
  cc_kernel<<<2, 256, 0, stream>>>(db2, gw1, gb1, cc);

  // weight products: {dw2, wq, wk} @ gw1 -> {Wp^T, Wqg^T, Wkg^T} (Bt-format)
  GP gwp{};
  gwp.Bt = gw1T;
  gwp.Aj[0] = dw2b; gwp.Cbj[0] = WpT;
  gwp.Aj[1] = wqb;  gwp.Cbj[1] = wBig + (size_t)512 * 512;
  gwp.Aj[2] = wkb;  gwp.Cbj[2] = wBig + (size_t)2 * 512 * 512;
  gemm_kernel<0, 4><<<dim3(4, 12), 256, 0, stream>>>(gwp);

  // fused projection: x @ [wv | wq@gw1 | wk@gw1] -> part-major {v, qg, kg}
  GP gq{};
  gq.A = xb; gq.Bt = wBig; gq.Cb = vqkg; gq.ldc = 1536;
  gemm_kernel<0, 6><<<dim3(12, 32), 256, 0, stream>>>(gq);

  // DUAL: A = h1 on the fly; pe = A@dw2T + db2 -> f32 attn region; h2 = relu(A@WpT + cc + qg - kg)
  GP gd{};
  gd.Bt = dw2T; gd.Bt2 = WpT; gd.Cf = attn_pe; gd.Cb = h2; gd.bias = db2;
  gd.xyz = xyz; gd.knn = knn; gd.dw1 = dw1; gd.db1 = db1;
  gd.cc = cc; gd.qkg = vqkg;
  gemm_kernel<2, 5><<<dim3(4, 512), 256, 0, stream>>>(gd);

  // gamma2 + softmax: a2 = h2 @ gw2 + gb2; attn in-place over pe; res_mid = sum attn*(v+pe)
  GP gs{};
  gs.A = h2; gs.Bt = gw2T; gs.bias = gb2;
  gs.knn = knn; gs.vb = vqkg; gs.pe_attn = attn_pe; gs.res_mid = res_mid;
  gemm_kernel<0, 3><<<dim3(4, 512), 256, 0, stream>>>(gs);

  final_kernel<<<512, 256, 0, stream>>>(res_mid, fc2_w, fc2_b, points, out);
}

// Round 9
// 436.658 us; speedup vs baseline: 1.1562x; 1.1479x over previous
//
#include <hip/hip_runtime.h>
#include <hip/hip_bf16.h>
#include <math.h>

typedef __bf16 bf16_t;
typedef float f32x4 __attribute__((ext_vector_type(4)));
typedef bf16_t bf16x8 __attribute__((ext_vector_type(8)));

#define BM 128
#define BN 128
#define BKT 32
#define NT 16    // 512 / BKT

// async global->LDS, 16B per lane; LDS dest = wave-uniform base + lane*16 (linear)
#define GLD_LDS16(gp, lp) __builtin_amdgcn_global_load_lds( \
    (const __attribute__((address_space(1))) void*)(gp), \
    (__attribute__((address_space(3))) void*)(lp), 16, 0, 0)

// ---------------- weight prep: jobs 0..3 transpose+cast, jobs 4..6 plain cast ----------------
struct TC7 { const float* src[7]; bf16_t* dst[7]; };
__global__ __launch_bounds__(256) void tcast7_kernel(TC7 tc) {
  int job = blockIdx.x >> 10;
  int idx = (blockIdx.x & 1023) * 256 + threadIdx.x;
  if (job < 4) {
    int n = idx >> 9, k = idx & 511;
    tc.dst[job][idx] = (bf16_t)tc.src[job][k * 512 + n];
  } else {
    tc.dst[job][idx] = (bf16_t)tc.src[job][idx];
  }
}

// ---------------- cc[n] = sum_d db2[d]*gw1[d][n] + gb1[n] ----------------
__global__ __launch_bounds__(256) void cc_kernel(const float* __restrict__ db2, const float* __restrict__ gw1,
                                                 const float* __restrict__ gb1, float* __restrict__ cc) {
  int n = blockIdx.x * 256 + threadIdx.x;
  float s = gb1[n];
  for (int d = 0; d < 512; ++d) s = fmaf(db2[d], gw1[d * 512 + n], s);
  cc[n] = s;
}

// ---------------- KNN: one WAVE per query; per-lane u64 keys in registers ----------------
__global__ __launch_bounds__(256) void knn_kernel(const float* __restrict__ xyz, int* __restrict__ knn) {
  __shared__ float sx[2048], sy[2048], sz[2048], sq[2048];
  int tid = threadIdx.x;
  int lane = tid & 63, wave = tid >> 6;
  int gq = blockIdx.x * 4 + wave;
  int b  = gq >> 11;
  int base = b << 11;
  for (int p = tid; p < 2048; p += 256) {
    float x = xyz[(base + p) * 3 + 0];
    float y = xyz[(base + p) * 3 + 1];
    float z = xyz[(base + p) * 3 + 2];
    sx[p] = x; sy[p] = y; sz[p] = z;
    sq[p] = __fadd_rn(__fadd_rn(__fmul_rn(x, x), __fmul_rn(y, y)), __fmul_rn(z, z));
  }
  __syncthreads();
  int iq = gq & 2047;
  float qx = sx[iq], qy = sy[iq], qz = sz[iq], sqi = sq[iq];

  unsigned long long key[32];
  #pragma unroll
  for (int j = 0; j < 32; ++j) {
    int p = lane + j * 64;
    float d = __fmul_rn(sx[p], qx);
    d = fmaf(sy[p], qy, d);
    d = fmaf(sz[p], qz, d);
    float dist = __fsub_rn(__fadd_rn(sqi, sq[p]), __fmul_rn(2.0f, d));
    unsigned int bits = __float_as_uint(dist);
    unsigned int sk = bits ^ (unsigned int)(((int)bits >> 31) | 0x80000000);
    key[j] = ((unsigned long long)sk << 32) | (unsigned int)p;
  }

  int r = 0;
  #pragma unroll 1
  for (int s = 0; s < 16; ++s) {
    unsigned long long m = key[0];
    #pragma unroll
    for (int j = 1; j < 32; ++j) m = (key[j] < m) ? key[j] : m;
    #pragma unroll
    for (int off = 32; off > 0; off >>= 1) {
      unsigned long long o = (unsigned long long)__shfl_xor((long long)m, off);
      if (o < m) m = o;
    }
    if (lane == s) r = base + (int)(m & 0xFFFFFFFFu);
    #pragma unroll
    for (int j = 0; j < 32; ++j) key[j] = (key[j] == m) ? ~0ULL : key[j];
  }
  if (lane < 16) knn[gq * 16 + lane] = r;
}

// ---------------- x = points @ fc1_w + fc1_b -> bf16 [4096][512] ----------------
__global__ __launch_bounds__(256) void xfeat_kernel(const float* __restrict__ points, const float* __restrict__ fc1_w,
                                                    const float* __restrict__ fc1_b, bf16_t* __restrict__ xb) {
  __shared__ float p[32];
  int m = blockIdx.x, tid = threadIdx.x;
  if (tid < 32) p[tid] = points[m * 32 + tid];
  __syncthreads();
  for (int c = tid; c < 512; c += 256) {
    float a = fc1_b[c];
    #pragma unroll
    for (int kk = 0; kk < 32; ++kk) a = fmaf(p[kk], fc1_w[kk * 512 + c], a);
    xb[m * 512 + c] = (bf16_t)a;
  }
}

// ---------------- res = res_mid @ fc2_w + fc2_b + points -> d_out[0:131072] ----------------
__global__ __launch_bounds__(256) void final_kernel(const float* __restrict__ res_mid, const float* __restrict__ fc2_w,
                                                    const float* __restrict__ fc2_b, const float* __restrict__ points,
                                                    float* __restrict__ out) {
  int oid = blockIdx.x * 256 + threadIdx.x;
  int m = oid >> 5, c = oid & 31;
  float a = fc2_b[c];
  const float* rm = res_mid + m * 512;
  for (int kk = 0; kk < 512; ++kk) a = fmaf(rm[kk], fc2_w[kk * 32 + c], a);
  out[oid] = a + points[oid];
}

// ---------------- MFMA GEMM engine, BKT=32, counted-vmcnt dbuf, OCCUPANCY-FIRST ----------------
// LDS 32KB (SRC0) / 40KB (SRC2) -> 5 / 4 blocks per CU; the resident waves provide the MLP that
// hides HBM latency (proven: R2/R3 high-occ >> R4-R8 low-occ). XOR swizzle: LDS slot s of row r
// holds global k-slot s^((r>>1)&3); reads 2-way max (free). Counted vmcnt keeps next stage in flight.
// SRC: 0 = A from global bf16 (gld_lds); 2 = h1 = relu(delta@dw1+db1) on the fly (dw1/db1 in LDS)
// EPI: 1 = +db2 -> pe bf16; 2 = relu(acc+cc+qg-kg) -> h2 bf16; 3 = softmax + attn f32 + res_mid;
//      4 = transposed bf16 w/ job-select (weight products); 6 = part-major bf16 (v|qg|kg)
struct GP {
  const bf16_t* A; const bf16_t* Bt;
  bf16_t* Cb; const float* bias; int ldc;
  const float* xyz; const int* knn; const float* dw1; const float* db1;
  const float* cc; const bf16_t* qkg;
  const bf16_t* vb; const bf16_t* peb; float* attn; float* res_mid;
  const bf16_t* Aj[3]; bf16_t* Cbj[3];
};

template <int SRC, int EPI>
__global__ __launch_bounds__(256) void gemm_kernel(GP gp) {
  __shared__ bf16_t Alds[2 * BM * BKT];
  __shared__ bf16_t Blds[2 * BN * BKT];
  __shared__ float  wl[(SRC == 2) ? 4 * 512 : 8];
  int tid  = threadIdx.x;
  int lane = tid & 63, wave = tid >> 6;
  int wr = wave >> 1, wc = wave & 1;
  int lr = lane & 15, lg = lane >> 4;

  // XCD-aware bijective swizzle (nwg % 8 == 0 for all launches)
  int gx = gridDim.x;
  int nwg = gx * gridDim.y;
  int orig = blockIdx.y * gx + blockIdx.x;
  int cpx = nwg >> 3;
  int swz = (orig & 7) * cpx + (orig >> 3);
  int bx = swz % gx;
  int by = swz / gx;
  int n0 = bx * BN;
  int m0 = ((EPI == 4) ? (by & 3) : by) * BM;
  const bf16_t* Aptr = (EPI == 4) ? gp.Aj[by >> 2] : gp.A;

  f32x4 acc[4][4];
  #pragma unroll
  for (int i = 0; i < 4; ++i)
    #pragma unroll
    for (int j = 0; j < 4; ++j) acc[i][j] = (f32x4){0.f, 0.f, 0.f, 0.f};

  int rS2 = tid >> 2;                                    // 0..63 staging row (and +64)
  int sl  = tid & 3;                                     // natural k-slot
  int swb = (rS2 >> 1) & 3;                              // row-swizzle bits
  int scS = ((sl ^ swb) << 3);                           // pre-swizzled source col (elements)

  float dx0, dy0, dz0, dx1, dy1, dz1;
  if (SRC == 2) {
    for (int c = tid; c < 512; c += 256) {
      wl[c]        = gp.dw1[c];
      wl[512 + c]  = gp.dw1[512 + c];
      wl[1024 + c] = gp.dw1[1024 + c];
      wl[1536 + c] = gp.db1[c];
    }
    int m_a = m0 + rS2, m_b = m0 + rS2 + 64;
    int ga = m_a >> 4, ja = gp.knn[m_a];
    int gb = m_b >> 4, jb = gp.knn[m_b];
    dx0 = gp.xyz[ga * 3 + 0] - gp.xyz[ja * 3 + 0];
    dy0 = gp.xyz[ga * 3 + 1] - gp.xyz[ja * 3 + 1];
    dz0 = gp.xyz[ga * 3 + 2] - gp.xyz[ja * 3 + 2];
    dx1 = gp.xyz[gb * 3 + 0] - gp.xyz[jb * 3 + 0];
    dy1 = gp.xyz[gb * 3 + 1] - gp.xyz[jb * 3 + 1];
    dz1 = gp.xyz[gb * 3 + 2] - gp.xyz[jb * 3 + 2];
    __syncthreads();   // wl ready (once)
  }

  auto stageA = [&](int t, int buf) {
    int k0 = t * BKT;
    if (SRC == 0) {
      GLD_LDS16(Aptr + (size_t)(m0 + rS2) * 512 + k0 + scS,       Alds + buf * (BM * BKT) + tid * 8);
      GLD_LDS16(Aptr + (size_t)(m0 + 64 + rS2) * 512 + k0 + scS,  Alds + buf * (BM * BKT) + 2048 + tid * 8);
    } else {
      int cb = k0 + sl * 8;
      f32x4 w0a = *(const f32x4*)(&wl[cb]),        w0b = *(const f32x4*)(&wl[cb + 4]);
      f32x4 w1a = *(const f32x4*)(&wl[512 + cb]),  w1b = *(const f32x4*)(&wl[512 + cb + 4]);
      f32x4 w2a = *(const f32x4*)(&wl[1024 + cb]), w2b = *(const f32x4*)(&wl[1024 + cb + 4]);
      f32x4 bba = *(const f32x4*)(&wl[1536 + cb]), bbb = *(const f32x4*)(&wl[1536 + cb + 4]);
      bf16_t* Ab = Alds + buf * (BM * BKT);
      bf16x8 o;
      #pragma unroll
      for (int u = 0; u < 4; ++u) {
        float h = fmaf(dz0, w2a[u], fmaf(dy0, w1a[u], dx0 * w0a[u])) + bba[u];
        o[u] = (bf16_t)fmaxf(h, 0.0f);
      }
      #pragma unroll
      for (int u = 0; u < 4; ++u) {
        float h = fmaf(dz0, w2b[u], fmaf(dy0, w1b[u], dx0 * w0b[u])) + bbb[u];
        o[4 + u] = (bf16_t)fmaxf(h, 0.0f);
      }
      *(bf16x8*)(&Ab[rS2 * BKT + (scS ^ 0)]) = o;   // slot sl^swb holds global slot sl
      #pragma unroll
      for (int u = 0; u < 4; ++u) {
        float h = fmaf(dz1, w2a[u], fmaf(dy1, w1a[u], dx1 * w0a[u])) + bba[u];
        o[u] = (bf16_t)fmaxf(h, 0.0f);
      }
      #pragma unroll
      for (int u = 0; u < 4; ++u) {
        float h = fmaf(dz1, w2b[u], fmaf(dy1, w1b[u], dx1 * w0b[u])) + bbb[u];
        o[4 + u] = (bf16_t)fmaxf(h, 0.0f);
      }
      *(bf16x8*)(&Ab[(rS2 + 64) * BKT + (scS ^ 0)]) = o;
    }
  };
  auto stageB = [&](int t, int buf) {
    int k0 = t * BKT;
    GLD_LDS16(gp.Bt + (size_t)(n0 + rS2) * 512 + k0 + scS,       Blds + buf * (BN * BKT) + tid * 8);
    GLD_LDS16(gp.Bt + (size_t)(n0 + 64 + rS2) * 512 + k0 + scS,  Blds + buf * (BN * BKT) + 2048 + tid * 8);
  };
  auto mfmaPhase = [&](int cur) {
    const bf16_t* Ab = Alds + cur * (BM * BKT);
    const bf16_t* Bb = Blds + cur * (BN * BKT);
    bf16x8 af[4], bfr[4];
    #pragma unroll
    for (int mi = 0; mi < 4; ++mi) {
      int rr = wr * 64 + mi * 16 + lr;
      af[mi] = *(const bf16x8*)(&Ab[rr * BKT + ((lg ^ ((rr >> 1) & 3)) << 3)]);
    }
    #pragma unroll
    for (int nj = 0; nj < 4; ++nj) {
      int rr = wc * 64 + nj * 16 + lr;
      bfr[nj] = *(const bf16x8*)(&Bb[rr * BKT + ((lg ^ ((rr >> 1) & 3)) << 3)]);
    }
    #pragma unroll
    for (int mi = 0; mi < 4; ++mi)
      #pragma unroll
      for (int nj = 0; nj < 4; ++nj)
        acc[mi][nj] = __builtin_amdgcn_mfma_f32_16x16x32_bf16(af[mi], bfr[nj], acc[mi][nj], 0, 0, 0);
  };

  stageA(0, 0);
  stageB(0, 0);

  #pragma unroll 1
  for (int t = 0; t < NT; ++t) {
    int cur = t & 1;
    if (t + 1 < NT) {
      stageA(t + 1, cur ^ 1);
      stageB(t + 1, cur ^ 1);
      if (SRC == 0) asm volatile("s_waitcnt vmcnt(4)" ::: "memory");
      else          asm volatile("s_waitcnt vmcnt(2) lgkmcnt(0)" ::: "memory");
    } else {
      asm volatile("s_waitcnt vmcnt(0) lgkmcnt(0)" ::: "memory");
    }
    __builtin_amdgcn_s_barrier();     // buf[cur] ready
    mfmaPhase(cur);
    __builtin_amdgcn_s_barrier();     // all waves done reading buf[cur]
  }

  if (EPI == 4) {
    bf16_t* CbT = gp.Cbj[by >> 2];
    #pragma unroll
    for (int mi = 0; mi < 4; ++mi)
      #pragma unroll
      for (int nj = 0; nj < 4; ++nj) {
        int col = n0 + wc * 64 + nj * 16 + lr;
        #pragma unroll
        for (int r = 0; r < 4; ++r) {
          int row = m0 + wr * 64 + mi * 16 + lg * 4 + r;
          CbT[(size_t)col * 512 + row] = (bf16_t)acc[mi][nj][r];
        }
      }
  } else if (EPI == 6) {
    #pragma unroll
    for (int mi = 0; mi < 4; ++mi)
      #pragma unroll
      for (int nj = 0; nj < 4; ++nj) {
        int col = n0 + wc * 64 + nj * 16 + lr;
        int part = col >> 9, c = col & 511;
        #pragma unroll
        for (int r = 0; r < 4; ++r) {
          int row = m0 + wr * 64 + mi * 16 + lg * 4 + r;
          gp.Cb[((size_t)part * 4096 + row) * 512 + c] = (bf16_t)acc[mi][nj][r];
        }
      }
  } else if (EPI == 1) {
    // pe = acc + db2 -> bf16
    #pragma unroll
    for (int mi = 0; mi < 4; ++mi)
      #pragma unroll
      for (int nj = 0; nj < 4; ++nj) {
        int col = n0 + wc * 64 + nj * 16 + lr;
        float bv = gp.bias[col];
        #pragma unroll
        for (int r = 0; r < 4; ++r) {
          int row = m0 + wr * 64 + mi * 16 + lg * 4 + r;
          gp.Cb[(size_t)row * 512 + col] = (bf16_t)(acc[mi][nj][r] + bv);
        }
      }
  } else if (EPI == 2) {
    // h2 = relu(acc + cc + qg - kg) -> bf16
    #pragma unroll
    for (int mi = 0; mi < 4; ++mi) {
      int g = (m0 + wr * 64 + mi * 16) >> 4;
      #pragma unroll
      for (int nj = 0; nj < 4; ++nj) {
        int col = n0 + wc * 64 + nj * 16 + lr;
        float ccv = gp.cc[col];
        float qgv = (float)gp.qkg[((size_t)4096 + g) * 512 + col];        // part1 = qg
        #pragma unroll
        for (int r = 0; r < 4; ++r) {
          int row = m0 + wr * 64 + mi * 16 + lg * 4 + r;
          int j = gp.knn[row];
          float kgv = (float)gp.qkg[((size_t)2 * 4096 + j) * 512 + col];  // part2 = kg
          float hv = acc[mi][nj][r] + ccv + qgv - kgv;
          gp.Cb[(size_t)row * 512 + col] = (bf16_t)fmaxf(hv, 0.0f);
        }
      }
    }
  } else {
    // EPI == 3: softmax over neighbors; attn f32 -> out region; res_mid partials
    const float scale = 22.62741699796952f;   // float(np.sqrt(512))
    #pragma unroll
    for (int mi = 0; mi < 4; ++mi) {
      int g = (m0 + wr * 64 + mi * 16) >> 4;
      #pragma unroll
      for (int nj = 0; nj < 4; ++nj) {
        int col = n0 + wc * 64 + nj * 16 + lr;
        float sv[4];
        float mx = -INFINITY;
        #pragma unroll
        for (int r = 0; r < 4; ++r) {
          sv[r] = (acc[mi][nj][r] + gp.bias[col]) / scale;
          mx = fmaxf(mx, sv[r]);
        }
        mx = fmaxf(mx, __shfl_xor(mx, 16));
        mx = fmaxf(mx, __shfl_xor(mx, 32));
        float e[4], sum = 0.f;
        #pragma unroll
        for (int r = 0; r < 4; ++r) { e[r] = expf(sv[r] - mx); sum += e[r]; }
        sum += __shfl_xor(sum, 16);
        sum += __shfl_xor(sum, 32);
        float part = 0.f;
        #pragma unroll
        for (int r = 0; r < 4; ++r) {
          int row = g * 16 + lg * 4 + r;
          float at = e[r] / sum;
          int j = gp.knn[row];
          float vv  = (float)gp.vb[(size_t)j * 512 + col];                // part0 = v
          float pev = (float)gp.peb[(size_t)row * 512 + col];
          part = fmaf(at, vv + pev, part);
          gp.attn[(size_t)row * 512 + col] = at;
        }
        part += __shfl_xor(part, 16);
        part += __shfl_xor(part, 32);
        if (lg == 0) gp.res_mid[(size_t)g * 512 + col] = part;
      }
    }
  }
}

extern "C" void kernel_launch(void* const* d_in, const int* in_sizes, int n_in,
                              void* d_out, int out_size, void* d_ws, size_t ws_size,
                              hipStream_t stream) {
  const float* xyz    = (const float*)d_in[0];
  const float* points = (const float*)d_in[1];
  const float* fc1_w  = (const float*)d_in[2];
  const float* fc1_b  = (const float*)d_in[3];
  const float* fc2_w  = (const float*)d_in[4];
  const float* fc2_b  = (const float*)d_in[5];
  const float* dw1    = (const float*)d_in[6];
  const float* db1    = (const float*)d_in[7];
  const float* dw2    = (const float*)d_in[8];
  const float* db2    = (const float*)d_in[9];
  const float* gw1    = (const float*)d_in[10];
  const float* gb1    = (const float*)d_in[11];
  const float* gw2    = (const float*)d_in[12];
  const float* gb2    = (const float*)d_in[13];
  const float* wq     = (const float*)d_in[14];
  const float* wk     = (const float*)d_in[15];
  const float* wv     = (const float*)d_in[16];

  float* out = (float*)d_out;
  float* attn = out + 131072;   // [65536][512] f32 attn output (written once, by g2)

  char* w = (char*)d_ws;
  bf16_t* wBig   = (bf16_t*)w; w += (size_t)1536 * 512 * 2;   // [wv^T | Wqg^T | Wkg^T]
  bf16_t* dw2T   = (bf16_t*)w; w += (size_t)512 * 512 * 2;
  bf16_t* gw1T   = (bf16_t*)w; w += (size_t)512 * 512 * 2;
  bf16_t* gw2T   = (bf16_t*)w; w += (size_t)512 * 512 * 2;
  bf16_t* dw2b   = (bf16_t*)w; w += (size_t)512 * 512 * 2;
  bf16_t* wqb    = (bf16_t*)w; w += (size_t)512 * 512 * 2;
  bf16_t* wkb    = (bf16_t*)w; w += (size_t)512 * 512 * 2;
  bf16_t* WpT    = (bf16_t*)w; w += (size_t)512 * 512 * 2;
  float*  cc     = (float*)w;  w += (size_t)512 * 4;
  int*    knn    = (int*)w;    w += (size_t)65536 * 4;
  bf16_t* xb     = (bf16_t*)w; w += (size_t)4096 * 512 * 2;
  bf16_t* vqkg   = (bf16_t*)w; w += (size_t)3 * 4096 * 512 * 2;  // part-major: v, qg, kg
  bf16_t* peb    = (bf16_t*)w; w += (size_t)65536 * 512 * 2;     // pe bf16
  bf16_t* h2     = (bf16_t*)w; w += (size_t)65536 * 512 * 2;
  float*  res_mid= (float*)w;  w += (size_t)4096 * 512 * 4;

  TC7 tc;
  tc.src[0] = wv;  tc.dst[0] = wBig;           // wv^T
  tc.src[1] = dw2; tc.dst[1] = dw2T;
  tc.src[2] = gw1; tc.dst[2] = gw1T;
  tc.src[3] = gw2; tc.dst[3] = gw2T;
  tc.src[4] = dw2; tc.dst[4] = dw2b;
  tc.src[5] = wq;  tc.dst[5] = wqb;
  tc.src[6] = wk;  tc.dst[6] = wkb;
  tcast7_kernel<<<7168, 256, 0, stream>>>(tc);

  knn_kernel<<<1024, 256, 0, stream>>>(xyz, knn);
  xfeat_kernel<<<4096, 256, 0, stream>>>(points, fc1_w, fc1_b, xb);
  cc_kernel<<<2, 256, 0, stream>>>(db2, gw1, gb1, cc);

  // weight products: {dw2, wq, wk} @ gw1 -> {Wp^T, Wqg^T, Wkg^T} (Bt-format)
  GP gwp{};
  gwp.Bt = gw1T;
  gwp.Aj[0] = dw2b; gwp.Cbj[0] = WpT;
  gwp.Aj[1] = wqb;  gwp.Cbj[1] = wBig + (size_t)512 * 512;
  gwp.Aj[2] = wkb;  gwp.Cbj[2] = wBig + (size_t)2 * 512 * 512;
  gemm_kernel<0, 4><<<dim3(4, 12), 256, 0, stream>>>(gwp);

  // fused projection: x @ [wv | wq@gw1 | wk@gw1] -> part-major {v, qg, kg}
  GP gq{};
  gq.A = xb; gq.Bt = wBig; gq.Cb = vqkg; gq.ldc = 1536;
  gemm_kernel<0, 6><<<dim3(12, 32), 256, 0, stream>>>(gq);

  // pe = h1(on the fly) @ dw2T + db2 -> bf16
  GP gpe{};
  gpe.Bt = dw2T; gpe.Cb = peb; gpe.bias = db2;
  gpe.xyz = xyz; gpe.knn = knn; gpe.dw1 = dw1; gpe.db1 = db1;
  gemm_kernel<2, 1><<<dim3(4, 512), 256, 0, stream>>>(gpe);

  // h2 = relu(h1(on the fly) @ WpT + cc + qg - kg) -> bf16
  GP gg{};
  gg.Bt = WpT; gg.Cb = h2;
  gg.xyz = xyz; gg.knn = knn; gg.dw1 = dw1; gg.db1 = db1;
  gg.cc = cc; gg.qkg = vqkg;
  gemm_kernel<2, 2><<<dim3(4, 512), 256, 0, stream>>>(gg);

  // gamma2 + softmax: a2 = h2 @ gw2 + gb2; attn f32 -> out; res_mid = sum attn*(v+pe)
  GP gs{};
  gs.A = h2; gs.Bt = gw2T; gs.bias = gb2;
  gs.knn = knn; gs.vb = vqkg; gs.peb = peb; gs.attn = attn; gs.res_mid = res_mid;
  gemm_kernel<0, 3><<<dim3(4, 512), 256, 0, stream>>>(gs);

  final_kernel<<<512, 256, 0, stream>>>(res_mid, fc2_w, fc2_b, points, out);
}